// Round 3
// baseline (210.923 us; speedup 1.0000x reference)
//
#include <hip/hip_runtime.h>

// Part_CAM: only parts e=1..4 survive feat_cam[:,1:].
// Row-0-of-chain: e0^T * (sub[11] @ ... @ sub[0]) as 12 vec-mat products.
// Round 3: full per-layer load hoisting into registers (addresses are
// data-independent) -> one memory-latency wait per layer instead of ~50.

#define L_ 12
#define B_ 64
#define N_ 201
#define D_ 768

template<int MAXRP>
__device__ __forceinline__ float vecmat_rows(const float* __restrict__ colp,
                                             const float* vin,
                                             int r0, int r1, int s, int e) {
    float xs[MAXRP];
    #pragma unroll
    for (int j = 0; j < MAXRP; ++j) {
        const int rr = r0 + j;
        if (rr < r1) {
            const int ra = (rr == 0) ? e : (s + rr - 1);
            xs[j] = colp[(size_t)ra * N_];
        }
    }
    float acc = 0.f;
    #pragma unroll
    for (int j = 0; j < MAXRP; ++j) {
        const int rr = r0 + j;
        if (rr < r1) acc += vin[rr] * xs[j];
    }
    return acc;
}

__global__ __launch_bounds__(1024) void part_cam_kernel(
    const float* __restrict__ x,     // (L, B, N, N)
    const float* __restrict__ feat,  // (B, N, D)
    float* __restrict__ out)         // (B, 4, D)
{
    const int p = blockIdx.x >> 6;   // 0..3  (part e = p+1)
    const int b = blockIdx.x & 63;
    const int e = p + 1;
    const int s = (p == 0) ? 5 : (p == 1) ? 5 : (p == 2) ? 54 : 103;
    const int t = (p == 0) ? 201 : (p == 1) ? 103 : (p == 2) ? 152 : 201;
    const int K = t - s;
    const int M = K + 1;             // 197 or 99
    const int tid = threadIdx.x;

    // vec-mat layout: columns x row-groups
    const int CW  = (p == 0) ? 256 : 128;   // column width
    const int RGS = (p == 0) ? 4 : 8;       // row groups
    const int c   = tid & (CW - 1);
    const int rg  = tid / CW;
    const int rows_per = (M + RGS - 1) / RGS;   // 50 or 13
    const int r0 = rg * rows_per;
    const int r1 = (r0 + rows_per < M) ? (r0 + rows_per) : M;

    __shared__ float bufA[256];
    __shared__ float bufB[256];
    __shared__ float vpart[1024];
    __shared__ float eacc[4 * 768];

    float* vin  = bufA;
    float* vout = bufB;

    const size_t mat_elems = (size_t)N_ * N_;
    const int mycol = (c == 0) ? e : (s + c - 1);   // idx[c]

    // v = row 0 of sub[11]  (row gather)
    if (tid < M) {
        const float* m11 = x + ((size_t)11 * B_ + b) * mat_elems;
        vin[tid] = m11[(size_t)e * N_ + ((tid == 0) ? e : (s + tid - 1))];
    }
    __syncthreads();

    // v <- v * sub[l]  for l = 10 .. 0, row-split, loads hoisted to regs
    for (int l = 10; l >= 0; --l) {
        const float* mat = x + ((size_t)l * B_ + b) * mat_elems;
        float acc = 0.f;
        if (c < M) {
            const float* colp = mat + mycol;
            acc = (p == 0) ? vecmat_rows<50>(colp, vin, r0, r1, s, e)
                           : vecmat_rows<13>(colp, vin, r0, r1, s, e);
        }
        vpart[tid] = acc;            // == vpart[rg*CW + c]
        __syncthreads();
        if (tid < M) {
            float sum = 0.f;
            #pragma unroll
            for (int g = 0; g < 8; ++g) {
                if (g < RGS) sum += vpart[g * CW + tid];
            }
            vout[tid] = sum;
        }
        __syncthreads();
        float* tmp = vin; vin = vout; vout = tmp;
    }

    // epilogue: cam[d] = sum_k v[1+k] * relu(feat[b, s+k, d]), k-split 4 ways,
    // feat loads hoisted 8 k's (24 loads) at a time
    const float* fb = feat + (size_t)b * N_ * D_;
    const int ed = tid & 255;
    const int eg = tid >> 8;              // 0..3
    const int kpg = (K + 3) >> 2;
    const int k0 = eg * kpg;
    const int k1 = (k0 + kpg < K) ? (k0 + kpg) : K;
    float a0 = 0.f, a1 = 0.f, a2 = 0.f;
    for (int k = k0; k < k1; k += 8) {
        float f0[8], f1[8], f2[8];
        #pragma unroll
        for (int j = 0; j < 8; ++j) {
            if (k + j < k1) {
                const float* frow = fb + (size_t)(s + k + j) * D_;
                f0[j] = frow[ed];
                f1[j] = frow[ed + 256];
                f2[j] = frow[ed + 512];
            }
        }
        #pragma unroll
        for (int j = 0; j < 8; ++j) {
            if (k + j < k1) {
                const float wk = vin[1 + k + j];
                a0 += wk * fmaxf(f0[j], 0.f);
                a1 += wk * fmaxf(f1[j], 0.f);
                a2 += wk * fmaxf(f2[j], 0.f);
            }
        }
    }
    eacc[eg * 768 + ed]       = a0;
    eacc[eg * 768 + ed + 256] = a1;
    eacc[eg * 768 + ed + 512] = a2;
    __syncthreads();
    if (tid < 768) {
        float sum = eacc[tid] + eacc[768 + tid] + eacc[1536 + tid] + eacc[2304 + tid];
        out[((size_t)b * 4 + p) * D_ + tid] = sum;
    }
}

extern "C" void kernel_launch(void* const* d_in, const int* in_sizes, int n_in,
                              void* d_out, int out_size, void* d_ws, size_t ws_size,
                              hipStream_t stream) {
    const float* x    = (const float*)d_in[0];
    const float* feat = (const float*)d_in[1];
    float* out = (float*)d_out;
    part_cam_kernel<<<dim3(256), dim3(1024), 0, stream>>>(x, feat, out);
}

// Round 4
// 159.924 us; speedup vs baseline: 1.3189x; 1.3189x over previous
//
#include <hip/hip_runtime.h>

// Part_CAM: only parts e=1..4 survive feat_cam[:,1:].
// Row-0-of-chain: e0^T * (sub[11] @ ... @ sub[0]) as 12 vec-mat products.
// Round 4: register-hoisted row loads sized to fit the 128-VGPR cap of a
// 1024-thread block (launch_bounds(1024,4)); cross-layer prefetch kept in
// flight across barriers via raw lgkmcnt-only barrier (no vmcnt drain).

#define L_ 12
#define B_ 64
#define N_ 201
#define D_ 768

// barrier that does NOT drain vmcnt: prefetch global loads stay in flight
#define BARRIER_LGKM() do { \
    asm volatile("s_waitcnt lgkmcnt(0)" ::: "memory"); \
    __builtin_amdgcn_s_barrier(); \
} while (0)

template<int RP, int CW, int RGS>
__device__ __forceinline__ float* run_chain(
    const float* __restrict__ x, int b, int e, int s, int M,
    float* vin, float* vout, float* vpart, int tid)
{
    const int c    = tid % CW;
    const int rg   = tid / CW;
    const int colc = (c < M) ? c : (M - 1);          // clamp pad lanes
    const int mycol = (colc == 0) ? e : (s + colc - 1);
    const int r0   = rg * RP;
    const size_t mat_elems = (size_t)N_ * N_;
    const bool wr = (rg < RGS);

    float xs[RP];

    // prefetch layer 10
    {
        const float* colp = x + ((size_t)10 * B_ + b) * mat_elems + mycol;
        #pragma unroll
        for (int j = 0; j < RP; ++j) {
            const int rr = r0 + j;
            const int rc = (rr < M) ? rr : (M - 1);  // clamp (dup loads ok)
            const int ra = (rc == 0) ? e : (s + rc - 1);
            xs[j] = colp[(size_t)ra * N_];
        }
    }

    for (int l = 10; l >= 0; --l) {
        // FMA current layer (vin tail beyond M is zeroed -> no predication)
        float acc = 0.f;
        #pragma unroll
        for (int j = 0; j < RP; ++j) {
            acc += vin[r0 + j] * xs[j];
        }
        // issue next layer's loads BEFORE the barriers; they stay in flight
        if (l > 0) {
            const float* colp = x + ((size_t)(l - 1) * B_ + b) * mat_elems + mycol;
            #pragma unroll
            for (int j = 0; j < RP; ++j) {
                const int rr = r0 + j;
                const int rc = (rr < M) ? rr : (M - 1);
                const int ra = (rc == 0) ? e : (s + rc - 1);
                xs[j] = colp[(size_t)ra * N_];
            }
        }
        if (wr) vpart[rg * CW + c] = acc;
        BARRIER_LGKM();
        if (tid < M) {
            float sum = 0.f;
            #pragma unroll
            for (int g = 0; g < RGS; ++g) sum += vpart[g * CW + tid];
            vout[tid] = sum;
        }
        BARRIER_LGKM();
        float* t = vin; vin = vout; vout = t;
    }
    return vin;
}

__global__ __launch_bounds__(1024, 4) void part_cam_kernel(
    const float* __restrict__ x,     // (L, B, N, N)
    const float* __restrict__ feat,  // (B, N, D)
    float* __restrict__ out)         // (B, 4, D)
{
    const int p = blockIdx.x >> 6;   // 0..3  (part e = p+1)
    const int b = blockIdx.x & 63;
    const int e = p + 1;
    const int s = (p == 0) ? 5 : (p == 1) ? 5 : (p == 2) ? 54 : 103;
    const int t = (p == 0) ? 201 : (p == 1) ? 103 : (p == 2) ? 152 : 201;
    const int K = t - s;
    const int M = K + 1;             // 197 or 99
    const int tid = threadIdx.x;

    __shared__ float bufA[256];
    __shared__ float bufB[256];
    __shared__ float vpart[1024];
    __shared__ float eacc[4 * 768];

    // zero v buffers (tails must be 0 so FMA can read unguarded), then gather
    if (tid < 256) { bufA[tid] = 0.f; bufB[tid] = 0.f; }
    if (tid < M) {
        const float* m11 = x + ((size_t)11 * B_ + b) * (size_t)(N_ * N_);
        bufA[tid] = m11[(size_t)e * N_ + ((tid == 0) ? e : (s + tid - 1))];
    }
    BARRIER_LGKM();

    float* vr;
    if (p == 0) vr = run_chain<40, 200, 5>(x, b, e, s, M, bufA, bufB, vpart, tid);
    else        vr = run_chain<10, 100, 10>(x, b, e, s, M, bufA, bufB, vpart, tid);

    // epilogue: cam[d] = sum_k v[1+k] * relu(feat[b, s+k, d]); k split 4 ways,
    // feat loads hoisted 16 rows (48 loads) at a time
    const float* fb = feat + (size_t)b * N_ * D_;
    const int ed = tid & 255;
    const int eg = tid >> 8;              // 0..3 (wave-uniform)
    const int kpg = (K + 3) >> 2;
    const int k0 = eg * kpg;
    const int k1 = (k0 + kpg < K) ? (k0 + kpg) : K;
    float a0 = 0.f, a1 = 0.f, a2 = 0.f;
    for (int k = k0; k < k1; k += 16) {
        float f0[16], f1[16], f2[16];
        #pragma unroll
        for (int j = 0; j < 16; ++j) {
            if (k + j < k1) {
                const float* frow = fb + (size_t)(s + k + j) * D_;
                f0[j] = frow[ed];
                f1[j] = frow[ed + 256];
                f2[j] = frow[ed + 512];
            }
        }
        #pragma unroll
        for (int j = 0; j < 16; ++j) {
            if (k + j < k1) {
                const float wk = vr[1 + k + j];
                a0 += wk * fmaxf(f0[j], 0.f);
                a1 += wk * fmaxf(f1[j], 0.f);
                a2 += wk * fmaxf(f2[j], 0.f);
            }
        }
    }
    eacc[eg * 768 + ed]       = a0;
    eacc[eg * 768 + ed + 256] = a1;
    eacc[eg * 768 + ed + 512] = a2;
    __syncthreads();
    if (tid < 768) {
        float sum = eacc[tid] + eacc[768 + tid] + eacc[1536 + tid] + eacc[2304 + tid];
        out[((size_t)b * 4 + p) * D_ + tid] = sum;
    }
}

extern "C" void kernel_launch(void* const* d_in, const int* in_sizes, int n_in,
                              void* d_out, int out_size, void* d_ws, size_t ws_size,
                              hipStream_t stream) {
    const float* x    = (const float*)d_in[0];
    const float* feat = (const float*)d_in[1];
    float* out = (float*)d_out;
    part_cam_kernel<<<dim3(256), dim3(1024), 0, stream>>>(x, feat, out);
}